// Round 1
// 2057.988 us; speedup vs baseline: 1.0824x; 1.0824x over previous
//
#include <hip/hip_runtime.h>

// ---------------------------------------------------------------------------
// GCKAN (3 layers) on MI355X — round 3: destination-sorted edges.
// The round-2 edge kernels were serialized on 128M random 4B atomicAdds
// (WRITE_SIZE == E*256*4 exactly -> every atomic was an HBM RMW).
// Counting-sort edges by col once, segment-reduce runs in LDS, write each
// (node,col) once (plain store for complete runs, atomic only at tile
// boundaries).
// ---------------------------------------------------------------------------

typedef __attribute__((ext_vector_type(4))) float f32x4;
typedef __attribute__((ext_vector_type(8))) short bf16x8;
typedef __attribute__((ext_vector_type(8))) unsigned short u16x8;
typedef __attribute__((ext_vector_type(4))) unsigned short u16x4;

__device__ __forceinline__ unsigned short f2bf(float f) {
    union { float f; unsigned u; } v; v.f = f;
    unsigned r = v.u + 0x7FFFu + ((v.u >> 16) & 1u);
    return (unsigned short)(r >> 16);
}

__device__ __forceinline__ float siluf(float x) {
    return x / (1.0f + __expf(-x));
}

// Expand scalar x -> 8 channels [silu, B0..B6]; cubic B-spline on uniform
// knots t_i = 0.5 i - 2.5 (matches reference Cox-de Boor exactly).
__device__ __forceinline__ void expand8(float x, float* o8) {
    float b[10];
#pragma unroll
    for (int i = 0; i < 10; ++i) {
        float ti = 0.5f * i - 2.5f;
        b[i] = (x >= ti && x < ti + 0.5f) ? 1.0f : 0.0f;
    }
#pragma unroll
    for (int j = 1; j <= 3; ++j) {
        float inv = 2.0f / (float)j;
#pragma unroll
        for (int i = 0; i < 10 - j; ++i) {
            float ti = 0.5f * i - 2.5f;
            float tj = 0.5f * (i + j + 1) - 2.5f;
            b[i] = (x - ti) * inv * b[i] + (tj - x) * inv * b[i + 1];
        }
    }
    o8[0] = siluf(x);
#pragma unroll
    for (int c = 0; c < 7; ++c) o8[c + 1] = b[c];
}

// ---------------------------------------------------------------------------
// Edge counting sort by destination (col). cursor[] doubles as histogram,
// then is scanned in place to bucket offsets, then consumed by the scatter.
// ---------------------------------------------------------------------------
__global__ __launch_bounds__(256) void k_hist(
    const int* __restrict__ col, int* __restrict__ cnt, int E) {
    int i = blockIdx.x * 256 + threadIdx.x;
    if (i < E) atomicAdd(&cnt[col[i]], 1);
}

// Single-block exclusive scan, in place. Wave-shuffle scan (2 barriers/chunk).
__global__ __launch_bounds__(1024) void k_scan(int* __restrict__ c, int N) {
    __shared__ int wsum[16];
    __shared__ int ctot;
    const int t = threadIdx.x;
    const int lane = t & 63, wid = t >> 6;
    int carry = 0;
    for (int base = 0; base < N; base += 1024) {
        int i = base + t;
        int v0 = (i < N) ? c[i] : 0;
        int v = v0;
#pragma unroll
        for (int off = 1; off < 64; off <<= 1) {
            int n = __shfl_up(v, (unsigned)off, 64);
            if (lane >= off) v += n;
        }
        if (lane == 63) wsum[wid] = v;
        __syncthreads();
        if (t < 16) {
            int s = wsum[t], sv = s;
#pragma unroll
            for (int off = 1; off < 16; off <<= 1) {
                int n = __shfl_up(sv, (unsigned)off, 16);
                if (t >= off) sv += n;
            }
            wsum[t] = sv - s;            // exclusive wave offset
            if (t == 15) ctot = sv;      // chunk total
        }
        __syncthreads();
        if (i < N) c[i] = carry + wsum[wid] + v - v0;  // exclusive scan
        carry += ctot;
        __syncthreads();                 // protect wsum/ctot for next chunk
    }
}

__global__ __launch_bounds__(256) void k_scatter(
    const int* __restrict__ row, const int* __restrict__ col,
    int* __restrict__ cursor, int* __restrict__ rowS,
    int* __restrict__ eidS, int* __restrict__ colS, int E) {
    int i = blockIdx.x * 256 + threadIdx.x;
    if (i < E) {
        int c = col[i];
        int p = atomicAdd(&cursor[c], 1);
        rowS[p] = row[i];
        eidS[p] = i;
        colS[p] = c;
    }
}

// ---------------------------------------------------------------------------
// Fused edge layer N=256 on DEST-SORTED edges.
// ea = EA[eid]@Wh^T + eb; msg = ea * XT[rowS]; segment-reduce runs of equal
// col in LDS; one store/atomic per (run, out-col).
// Tile: 64 sorted edges x 256 outs, 4 waves, K-step 32.
// LDS: staging (20.5KB) union msg tile [64][130] f32 (33.3KB) -> 4 blk/CU.
// ---------------------------------------------------------------------------
__global__ __launch_bounds__(256) void edge_mfma256_s(
    const float* __restrict__ EA, const unsigned short* __restrict__ Wh,
    const float* __restrict__ eb, const float* __restrict__ XT,
    const int* __restrict__ rowS, const int* __restrict__ colS,
    const int* __restrict__ eidS, float* __restrict__ AGG, int E) {
    __shared__ __align__(16) char smem[64 * 130 * 4];   // 33280 B
    unsigned short (*As)[64][8]  = (unsigned short (*)[64][8])smem;          // 4 KB
    unsigned short (*Bs)[256][8] = (unsigned short (*)[256][8])(smem + 4096); // 16 KB
    float (*MSG)[130] = (float (*)[130])smem;            // union, used after K loop
    __shared__ int cols_s[64];
    __shared__ int runst[65];
    __shared__ int runc[64];
    __shared__ int nruns;

    const int tid = threadIdx.x;
    const int wv = tid >> 6, lane = tid & 63;
    const int l15 = lane & 15, l4 = lane >> 4;
    const long m0 = (long)blockIdx.x * 64;
    f32x4 acc[4][4] = {};

    // ---- run table for this tile (cols are globally non-decreasing) ----
    if (tid < 64) {
        long p = m0 + tid;
        cols_s[tid] = (p < E) ? colS[p] : -1;
    }
    __syncthreads();
    if (tid == 0) {
        int nr = 0, prev = -2;
        for (int e = 0; e < 64; ++e) {
            int cc = cols_s[e];
            if (cc != prev) { runst[nr] = e; runc[nr] = cc; prev = cc; ++nr; }
        }
        runst[nr] = 64;
        nruns = nr;
    }
    // visibility of runst/runc/nruns guaranteed by K-loop barriers

    const int sr = tid >> 2;      // A-stage row 0..63 (sorted position)
    const int sg = tid & 3;       // A-stage k-group
    const long arow = m0 + sr;
    const bool aok = arow < E;
    const long eid = aok ? (long)eidS[arow] : 0;
    const float* aptr = EA + eid * 384 + sg * 8;
    const unsigned short* bptr = Wh + (long)tid * 384;

    for (int it = 0; it < 12; ++it) {
        const int k0 = it * 32;
        u16x8 ap = {};
        if (aok) {
            float4 v0 = *(const float4*)(aptr + k0);
            float4 v1 = *(const float4*)(aptr + k0 + 4);
            ap[0] = f2bf(v0.x); ap[1] = f2bf(v0.y); ap[2] = f2bf(v0.z); ap[3] = f2bf(v0.w);
            ap[4] = f2bf(v1.x); ap[5] = f2bf(v1.y); ap[6] = f2bf(v1.z); ap[7] = f2bf(v1.w);
        }
        u16x8 b0 = *(const u16x8*)(bptr + k0);
        u16x8 b1 = *(const u16x8*)(bptr + k0 + 8);
        u16x8 b2 = *(const u16x8*)(bptr + k0 + 16);
        u16x8 b3 = *(const u16x8*)(bptr + k0 + 24);
        __syncthreads();
        *(u16x8*)&As[sg][sr][0] = ap;
        *(u16x8*)&Bs[0][tid][0] = b0;
        *(u16x8*)&Bs[1][tid][0] = b1;
        *(u16x8*)&Bs[2][tid][0] = b2;
        *(u16x8*)&Bs[3][tid][0] = b3;
        __syncthreads();
        bf16x8 af[4], bfv[4];
#pragma unroll
        for (int mi = 0; mi < 4; ++mi)
            af[mi] = *(const bf16x8*)&As[l4][mi * 16 + l15][0];
#pragma unroll
        for (int nj = 0; nj < 4; ++nj)
            bfv[nj] = *(const bf16x8*)&Bs[l4][wv * 64 + nj * 16 + l15][0];
#pragma unroll
        for (int mi = 0; mi < 4; ++mi)
#pragma unroll
            for (int nj = 0; nj < 4; ++nj)
                acc[mi][nj] = __builtin_amdgcn_mfma_f32_16x16x32_bf16(
                    af[mi], bfv[nj], acc[mi][nj], 0, 0, 0);
    }

    const int nb = wv * 64;
    float bs[4];
#pragma unroll
    for (int nj = 0; nj < 4; ++nj) bs[nj] = eb[nb + nj * 16 + l15];

    // Two column phases of 128 so the msg tile fits in the staging union.
#pragma unroll
    for (int p = 0; p < 2; ++p) {
        __syncthreads();   // staging reads / previous-phase reduce done
        if ((wv >> 1) == p) {
            const int cb = nb - p * 128;   // 0 or 64
#pragma unroll
            for (int mi = 0; mi < 4; ++mi) {
#pragma unroll
                for (int r = 0; r < 4; ++r) {
                    long e = m0 + mi * 16 + l4 * 4 + r;
                    if (e < E) {
                        int rn = rowS[e];
                        const float* xr = XT + (long)rn * 256 + nb + l15;
                        float* mrow = &MSG[mi * 16 + l4 * 4 + r][cb + l15];
#pragma unroll
                        for (int nj = 0; nj < 4; ++nj)
                            mrow[nj * 16] = (acc[mi][nj][r] + bs[nj]) * xr[nj * 16];
                    }
                }
            }
        }
        __syncthreads();
        // reduce: thread owns (col = tid&127, run parity g = tid>>7)
        const int colv = tid & 127, g = tid >> 7;
        const int nr = nruns;
        for (int ri = g; ri < nr; ri += 2) {
            int cc = runc[ri];
            if (cc < 0) continue;                 // padded tail
            int a = runst[ri], b = runst[ri + 1];
            float s = 0.f;
            for (int e = a; e < b; ++e) s += MSG[e][colv];
            float* dst = AGG + (long)cc * 256 + p * 128 + colv;
            if (a > 0 && b < 64) *dst = s;        // node fully inside tile
            else atomicAdd(dst, s);               // boundary run
        }
    }
}

// ---------------------------------------------------------------------------
// Node GEMM N=256: Y = X(M,K)@Wh(256,K)^T + bias.
// ---------------------------------------------------------------------------
template <int K>
__global__ __launch_bounds__(256) void node_mfma(
    const float* __restrict__ X, const unsigned short* __restrict__ Wh,
    const float* __restrict__ bias, float* __restrict__ Y, int M) {
    __shared__ __align__(16) unsigned short As[4][64][8];
    __shared__ __align__(16) unsigned short Bs[4][256][8];
    const int tid = threadIdx.x;
    const int wv = tid >> 6, lane = tid & 63;
    const int l15 = lane & 15, l4 = lane >> 4;
    const long m0 = (long)blockIdx.x * 64;
    f32x4 acc[4][4] = {};

    const int sr = tid >> 2, sg = tid & 3;
    const long arow = m0 + sr;
    const float* aptr = X + arow * K + sg * 8;
    const bool aok = arow < M;
    const unsigned short* bptr = Wh + (long)tid * K;

    for (int it = 0; it < K / 32; ++it) {
        const int k0 = it * 32;
        u16x8 ap = {};
        if (aok) {
            float4 v0 = *(const float4*)(aptr + k0);
            float4 v1 = *(const float4*)(aptr + k0 + 4);
            ap[0] = f2bf(v0.x); ap[1] = f2bf(v0.y); ap[2] = f2bf(v0.z); ap[3] = f2bf(v0.w);
            ap[4] = f2bf(v1.x); ap[5] = f2bf(v1.y); ap[6] = f2bf(v1.z); ap[7] = f2bf(v1.w);
        }
        u16x8 b0 = *(const u16x8*)(bptr + k0);
        u16x8 b1 = *(const u16x8*)(bptr + k0 + 8);
        u16x8 b2 = *(const u16x8*)(bptr + k0 + 16);
        u16x8 b3 = *(const u16x8*)(bptr + k0 + 24);
        __syncthreads();
        *(u16x8*)&As[sg][sr][0] = ap;
        *(u16x8*)&Bs[0][tid][0] = b0;
        *(u16x8*)&Bs[1][tid][0] = b1;
        *(u16x8*)&Bs[2][tid][0] = b2;
        *(u16x8*)&Bs[3][tid][0] = b3;
        __syncthreads();
        bf16x8 af[4], bfv[4];
#pragma unroll
        for (int mi = 0; mi < 4; ++mi)
            af[mi] = *(const bf16x8*)&As[l4][mi * 16 + l15][0];
#pragma unroll
        for (int nj = 0; nj < 4; ++nj)
            bfv[nj] = *(const bf16x8*)&Bs[l4][wv * 64 + nj * 16 + l15][0];
#pragma unroll
        for (int mi = 0; mi < 4; ++mi)
#pragma unroll
            for (int nj = 0; nj < 4; ++nj)
                acc[mi][nj] = __builtin_amdgcn_mfma_f32_16x16x32_bf16(
                    af[mi], bfv[nj], acc[mi][nj], 0, 0, 0);
    }

    const int nb = wv * 64;
    float bs[4];
#pragma unroll
    for (int nj = 0; nj < 4; ++nj) bs[nj] = bias[nb + nj * 16 + l15];
#pragma unroll
    for (int mi = 0; mi < 4; ++mi) {
#pragma unroll
        for (int r = 0; r < 4; ++r) {
            long gm = m0 + mi * 16 + l4 * 4 + r;
            if (gm < M) {
#pragma unroll
                for (int nj = 0; nj < 4; ++nj)
                    Y[gm * 256 + nb + nj * 16 + l15] = acc[mi][nj][r] + bs[nj];
            }
        }
    }
}

// ---------------------------------------------------------------------------
// KAN linear N=256: Y = expand8(AGG)(M,2048) @ Wch(256,2048)^T.
// ---------------------------------------------------------------------------
__global__ __launch_bounds__(256) void kan_mfma256(
    const float* __restrict__ AGG, const unsigned short* __restrict__ Wch,
    float* __restrict__ Y, int M) {
    __shared__ __align__(16) unsigned short As[4][64][8];
    __shared__ __align__(16) unsigned short Bs[4][256][8];
    const int tid = threadIdx.x;
    const int wv = tid >> 6, lane = tid & 63;
    const int l15 = lane & 15, l4 = lane >> 4;
    const long m0 = (long)blockIdx.x * 64;
    f32x4 acc[4][4] = {};

    const int srow = tid & 63, sg = tid >> 6;
    const long arow = m0 + srow;
    const bool aok = arow < M;
    const float* aptr = AGG + arow * 256 + sg;
    const unsigned short* bptr = Wch + (long)tid * 2048;

    for (int it = 0; it < 64; ++it) {
        float xv = aok ? aptr[it * 4] : 0.f;
        float e8[8];
        expand8(xv, e8);
        u16x8 ap;
#pragma unroll
        for (int c = 0; c < 8; ++c) ap[c] = f2bf(e8[c]);
        const int k0 = it * 32;
        u16x8 b0 = *(const u16x8*)(bptr + k0);
        u16x8 b1 = *(const u16x8*)(bptr + k0 + 8);
        u16x8 b2 = *(const u16x8*)(bptr + k0 + 16);
        u16x8 b3 = *(const u16x8*)(bptr + k0 + 24);
        __syncthreads();
        *(u16x8*)&As[sg][srow][0] = ap;
        *(u16x8*)&Bs[0][tid][0] = b0;
        *(u16x8*)&Bs[1][tid][0] = b1;
        *(u16x8*)&Bs[2][tid][0] = b2;
        *(u16x8*)&Bs[3][tid][0] = b3;
        __syncthreads();
        bf16x8 af[4], bfv[4];
#pragma unroll
        for (int mi = 0; mi < 4; ++mi)
            af[mi] = *(const bf16x8*)&As[l4][mi * 16 + l15][0];
#pragma unroll
        for (int nj = 0; nj < 4; ++nj)
            bfv[nj] = *(const bf16x8*)&Bs[l4][wv * 64 + nj * 16 + l15][0];
#pragma unroll
        for (int mi = 0; mi < 4; ++mi)
#pragma unroll
            for (int nj = 0; nj < 4; ++nj)
                acc[mi][nj] = __builtin_amdgcn_mfma_f32_16x16x32_bf16(
                    af[mi], bfv[nj], acc[mi][nj], 0, 0, 0);
    }

    const int nb = wv * 64;
#pragma unroll
    for (int mi = 0; mi < 4; ++mi) {
#pragma unroll
        for (int r = 0; r < 4; ++r) {
            long gm = m0 + mi * 16 + l4 * 4 + r;
            if (gm < M) {
#pragma unroll
                for (int nj = 0; nj < 4; ++nj)
                    Y[gm * 256 + nb + nj * 16 + l15] = acc[mi][nj][r];
            }
        }
    }
}

// ---------------------------------------------------------------------------
// Fused edge layer N=32 (output layer) on DEST-SORTED edges.
// Tile 256 sorted edges x 32 outs; LDS msg tile [256][34] f32 union staging.
// ---------------------------------------------------------------------------
__global__ __launch_bounds__(256) void edge_mfma32_s(
    const float* __restrict__ EA, const unsigned short* __restrict__ Wh,
    const float* __restrict__ eb, const float* __restrict__ XT,
    const int* __restrict__ rowS, const int* __restrict__ colS,
    const int* __restrict__ eidS, float* __restrict__ AGG, int E) {
    __shared__ __align__(16) char smem[256 * 34 * 4];   // 34816 B
    unsigned short (*As)[256][8] = (unsigned short (*)[256][8])smem;            // 16 KB
    unsigned short (*Bs)[32][8]  = (unsigned short (*)[32][8])(smem + 16384);   // 2 KB
    float (*MSG)[34] = (float (*)[34])smem;              // union, after K loop
    __shared__ int cols_s[256];
    __shared__ int runst[257];
    __shared__ int runc[256];
    __shared__ int nruns;

    const int tid = threadIdx.x;
    const int wv = tid >> 6, lane = tid & 63;
    const int l15 = lane & 15, l4 = lane >> 4;
    const long m0 = (long)blockIdx.x * 256;
    f32x4 acc[4][2] = {};

    {
        long p = m0 + tid;
        cols_s[tid] = (p < E) ? colS[p] : -1;
    }
    __syncthreads();
    if (tid == 0) {
        int nr = 0, prev = -2;
        for (int e = 0; e < 256; ++e) {
            int cc = cols_s[e];
            if (cc != prev) { runst[nr] = e; runc[nr] = cc; prev = cc; ++nr; }
        }
        runst[nr] = 256;
        nruns = nr;
    }

    const int sr = tid >> 3;          // 0..31, rows sr + 32*j
    const int sq = (tid & 7) * 4;     // k offset 0..28
    const int sg2 = sq >> 3, so2 = sq & 7;

    int eidv[8];
#pragma unroll
    for (int j = 0; j < 8; ++j) {
        long p = m0 + j * 32 + sr;
        eidv[j] = (p < E) ? eidS[p] : -1;
    }

    for (int it = 0; it < 12; ++it) {
        const int k0 = it * 32;
        float4 va[8];
#pragma unroll
        for (int j = 0; j < 8; ++j)
            va[j] = (eidv[j] >= 0) ? *(const float4*)(EA + (long)eidv[j] * 384 + k0 + sq)
                                   : make_float4(0.f, 0.f, 0.f, 0.f);
        u16x8 bv = {};
        if (tid < 128)
            bv = *(const u16x8*)(Wh + (long)(tid >> 2) * 384 + k0 + (tid & 3) * 8);
        __syncthreads();
#pragma unroll
        for (int j = 0; j < 8; ++j) {
            u16x4 ap;
            ap[0] = f2bf(va[j].x); ap[1] = f2bf(va[j].y);
            ap[2] = f2bf(va[j].z); ap[3] = f2bf(va[j].w);
            *(u16x4*)&As[sg2][j * 32 + sr][so2] = ap;
        }
        if (tid < 128) *(u16x8*)&Bs[tid & 3][tid >> 2][0] = bv;
        __syncthreads();
        bf16x8 af[4], bfv[2];
#pragma unroll
        for (int mi = 0; mi < 4; ++mi)
            af[mi] = *(const bf16x8*)&As[l4][wv * 64 + mi * 16 + l15][0];
#pragma unroll
        for (int nj = 0; nj < 2; ++nj)
            bfv[nj] = *(const bf16x8*)&Bs[l4][nj * 16 + l15][0];
#pragma unroll
        for (int mi = 0; mi < 4; ++mi)
#pragma unroll
            for (int nj = 0; nj < 2; ++nj)
                acc[mi][nj] = __builtin_amdgcn_mfma_f32_16x16x32_bf16(
                    af[mi], bfv[nj], acc[mi][nj], 0, 0, 0);
    }

    float bs2[2];
#pragma unroll
    for (int nj = 0; nj < 2; ++nj) bs2[nj] = eb[nj * 16 + l15];

    __syncthreads();   // staging reads done; reuse smem as MSG
#pragma unroll
    for (int mi = 0; mi < 4; ++mi) {
#pragma unroll
        for (int r = 0; r < 4; ++r) {
            int el = wv * 64 + mi * 16 + l4 * 4 + r;
            long e = m0 + el;
            if (e < E) {
                int rn = rowS[e];
#pragma unroll
                for (int nj = 0; nj < 2; ++nj) {
                    int o = nj * 16 + l15;
                    MSG[el][o] = (acc[mi][nj][r] + bs2[nj]) * XT[(long)rn * 32 + o];
                }
            }
        }
    }
    __syncthreads();
    const int colv = tid & 31, g = tid >> 5;   // 8 run groups x 32 cols
    const int nr = nruns;
    for (int ri = g; ri < nr; ri += 8) {
        int cc = runc[ri];
        if (cc < 0) continue;
        int a = runst[ri], b = runst[ri + 1];
        float s = 0.f;
        for (int e = a; e < b; ++e) s += MSG[e][colv];
        float* dst = AGG + (long)cc * 32 + colv;
        if (a > 0 && b < 256) *dst = s;
        else atomicAdd(dst, s);
    }
}

// ---------------------------------------------------------------------------
// Node GEMM for concat input, N=32: Y = [x|h0|h1](M,768) @ Wh(32,768)^T + b.
// ---------------------------------------------------------------------------
__global__ __launch_bounds__(256) void node_cat_mfma(
    const float* __restrict__ X, const float* __restrict__ H0,
    const float* __restrict__ H1, const unsigned short* __restrict__ Wh,
    const float* __restrict__ bias, float* __restrict__ Y, int M) {
    __shared__ __align__(16) unsigned short As[4][256][8];
    __shared__ __align__(16) unsigned short Bs[4][32][8];
    const int tid = threadIdx.x;
    const int wv = tid >> 6, lane = tid & 63;
    const int l15 = lane & 15, l4 = lane >> 4;
    const long m0 = (long)blockIdx.x * 256;
    f32x4 acc[4][2] = {};

    const int sr = tid >> 3;
    const int sq = (tid & 7) * 4;
    const int sg2 = sq >> 3, so2 = sq & 7;

    for (int it = 0; it < 24; ++it) {
        const int k0 = it * 32;
        const float* src = (it < 8) ? X : (it < 16) ? H0 : H1;
        const int kk = k0 & 255;
        float4 va[8];
#pragma unroll
        for (int j = 0; j < 8; ++j) {
            long r_ = m0 + j * 32 + sr;
            va[j] = (r_ < M) ? *(const float4*)(src + r_ * 256 + kk + sq)
                             : make_float4(0.f, 0.f, 0.f, 0.f);
        }
        u16x8 bv = {};
        if (tid < 128)
            bv = *(const u16x8*)(Wh + (long)(tid >> 2) * 768 + k0 + (tid & 3) * 8);
        __syncthreads();
#pragma unroll
        for (int j = 0; j < 8; ++j) {
            u16x4 ap;
            ap[0] = f2bf(va[j].x); ap[1] = f2bf(va[j].y);
            ap[2] = f2bf(va[j].z); ap[3] = f2bf(va[j].w);
            *(u16x4*)&As[sg2][j * 32 + sr][so2] = ap;
        }
        if (tid < 128) *(u16x8*)&Bs[tid & 3][tid >> 2][0] = bv;
        __syncthreads();
        bf16x8 af[4], bfv[2];
#pragma unroll
        for (int mi = 0; mi < 4; ++mi)
            af[mi] = *(const bf16x8*)&As[l4][wv * 64 + mi * 16 + l15][0];
#pragma unroll
        for (int nj = 0; nj < 2; ++nj)
            bfv[nj] = *(const bf16x8*)&Bs[l4][nj * 16 + l15][0];
#pragma unroll
        for (int mi = 0; mi < 4; ++mi)
#pragma unroll
            for (int nj = 0; nj < 2; ++nj)
                acc[mi][nj] = __builtin_amdgcn_mfma_f32_16x16x32_bf16(
                    af[mi], bfv[nj], acc[mi][nj], 0, 0, 0);
    }

#pragma unroll
    for (int mi = 0; mi < 4; ++mi) {
#pragma unroll
        for (int r = 0; r < 4; ++r) {
            long gm = m0 + wv * 64 + mi * 16 + l4 * 4 + r;
            if (gm < M) {
#pragma unroll
                for (int nj = 0; nj < 2; ++nj) {
                    int o = nj * 16 + l15;
                    Y[gm * 32 + o] = acc[mi][nj][r] + bias[o];
                }
            }
        }
    }
}

// ---------------------------------------------------------------------------
// Small f32 KAN for output layer (M x 32 -> M x 32).
// ---------------------------------------------------------------------------
__global__ __launch_bounds__(256) void kan_gemm32(
    const float* __restrict__ AGG, const float* __restrict__ Wc,
    float* __restrict__ Y, int M) {
    __shared__ float As[64][36];
    __shared__ float Bs[32][36];
    const int tid = threadIdx.x;
    const int tx = tid & 15, ty = tid >> 4;
    const int m0 = blockIdx.x * 64;
    float acc[4][2] = {{0.f, 0.f}, {0.f, 0.f}, {0.f, 0.f}, {0.f, 0.f}};
    const int er = tid >> 2, ef = tid & 3;
    const int em = m0 + er;
    for (int ic = 0; ic < 32; ic += 4) {
        float xv = (em < M) ? AGG[(long)em * 32 + ic + ef] : 0.f;
        float e8[8];
        expand8(xv, e8);
        *(float4*)&As[er][ef * 8] = make_float4(e8[0], e8[1], e8[2], e8[3]);
        *(float4*)&As[er][ef * 8 + 4] = make_float4(e8[4], e8[5], e8[6], e8[7]);
        {
            int o = tid >> 3, k4 = (tid & 7) * 4;
            *(float4*)&Bs[o][k4] = *(const float4*)&Wc[(long)o * 256 + ic * 8 + k4];
        }
        __syncthreads();
#pragma unroll
        for (int kk = 0; kk < 32; ++kk) {
            float a_[4], b_[2];
#pragma unroll
            for (int i = 0; i < 4; ++i) a_[i] = As[ty * 4 + i][kk];
#pragma unroll
            for (int j = 0; j < 2; ++j) b_[j] = Bs[tx * 2 + j][kk];
#pragma unroll
            for (int i = 0; i < 4; ++i)
#pragma unroll
                for (int j = 0; j < 2; ++j) acc[i][j] = fmaf(a_[i], b_[j], acc[i][j]);
        }
        __syncthreads();
    }
#pragma unroll
    for (int i = 0; i < 4; ++i) {
        int gm = m0 + ty * 4 + i;
        if (gm >= M) continue;
#pragma unroll
        for (int j = 0; j < 2; ++j) Y[(long)gm * 32 + tx * 2 + j] = acc[i][j];
    }
}

// ---------------------------------------------------------------------------
// Weight prep
// ---------------------------------------------------------------------------
__global__ __launch_bounds__(256) void cvt_bf16(
    const float* __restrict__ s, unsigned short* __restrict__ d, int n) {
    int i = blockIdx.x * 256 + threadIdx.x;
    if (i < n) d[i] = f2bf(s[i]);
}

__global__ __launch_bounds__(256) void pack_kan_bf16(
    const float* __restrict__ baseW, const float* __restrict__ splineW,
    unsigned short* __restrict__ Wc, int n) {
    int idx = blockIdx.x * 256 + threadIdx.x;
    if (idx >= n) return;
    unsigned short* dst = Wc + (long)idx * 8;
    dst[0] = f2bf(baseW[idx]);
    const float* sw = splineW + (long)idx * 7;
#pragma unroll
    for (int c = 0; c < 7; ++c) dst[1 + c] = f2bf(sw[c]);
}

__global__ __launch_bounds__(256) void pack_kan_f32(
    const float* __restrict__ baseW, const float* __restrict__ splineW,
    float* __restrict__ Wc, int n) {
    int idx = blockIdx.x * 256 + threadIdx.x;
    if (idx >= n) return;
    float* dst = Wc + (long)idx * 8;
    dst[0] = baseW[idx];
    const float* sw = splineW + (long)idx * 7;
#pragma unroll
    for (int c = 0; c < 7; ++c) dst[1 + c] = sw[c];
}

// ---------------------------------------------------------------------------
extern "C" void kernel_launch(void* const* d_in, const int* in_sizes, int n_in,
                              void* d_out, int out_size, void* d_ws, size_t ws_size,
                              hipStream_t stream) {
    const float* x          = (const float*)d_in[0];
    const int*   edge_index = (const int*)d_in[1];
    const float* edge_attr  = (const float*)d_in[2];
    const float* node_W0 = (const float*)d_in[3];
    const float* node_b0 = (const float*)d_in[4];
    const float* edge_W0 = (const float*)d_in[5];
    const float* edge_b0 = (const float*)d_in[6];
    const float* base_W0 = (const float*)d_in[7];
    const float* spline_W0 = (const float*)d_in[8];
    const float* node_W1 = (const float*)d_in[9];
    const float* node_b1 = (const float*)d_in[10];
    const float* edge_W1 = (const float*)d_in[11];
    const float* edge_b1 = (const float*)d_in[12];
    const float* base_W1 = (const float*)d_in[13];
    const float* spline_W1 = (const float*)d_in[14];
    const float* node_Wo = (const float*)d_in[15];
    const float* node_bo = (const float*)d_in[16];
    const float* edge_Wo = (const float*)d_in[17];
    const float* edge_bo = (const float*)d_in[18];
    const float* base_Wo = (const float*)d_in[19];
    const float* spline_Wo = (const float*)d_in[20];
    float* out = (float*)d_out;

    const int N = in_sizes[0] / 256;
    const int E = in_sizes[1] / 2;

    float* ws  = (float*)d_ws;
    float* xt  = ws;                       // N*256 (also (N,32) for out layer)
    float* agg = xt + (long)N * 256;       // N*256 (also (N,32) for out layer)
    float* h0  = agg + (long)N * 256;
    float* h1  = h0 + (long)N * 256;
    float* Wco = h1 + (long)N * 256;       // 32*256 f32 (packed KAN out)
    unsigned short* Wc0h = (unsigned short*)(Wco + 32 * 256);
    unsigned short* Wc1h = Wc0h + 256 * 2048;
    unsigned short* eW0h = Wc1h + 256 * 2048;
    unsigned short* eW1h = eW0h + 256 * 384;
    unsigned short* eWoh = eW1h + 256 * 384;
    unsigned short* nW0h = eWoh + 32 * 384;
    unsigned short* nW1h = nW0h + 256 * 256;
    unsigned short* nWoh = nW1h + 256 * 256;   // 32*768
    int* cursor = (int*)(nWoh + 32 * 768);     // N+1 ints (hist -> scan -> scatter)
    int* rowS   = cursor + (N + 1);            // E ints: src row, sorted by col
    int* eidS   = rowS + E;                    // E ints: original edge id
    int* colS   = eidS + E;                    // E ints: sorted col (non-decreasing)

    const int* row = edge_index;
    const int* col = edge_index + E;

    const int nb64 = (N + 63) / 64;
    const int eb64 = (E + 63) / 64;
    const int eb256 = (E + 255) / 256;
    const int nb256 = (N + 255) / 256;

    // ---- counting sort of edges by destination (shared by all 3 layers) ----
    hipMemsetAsync(cursor, 0, (size_t)(N + 1) * sizeof(int), stream);
    k_hist<<<eb256, 256, 0, stream>>>(col, cursor, E);
    k_scan<<<1, 1024, 0, stream>>>(cursor, N);
    k_scatter<<<eb256, 256, 0, stream>>>(row, col, cursor, rowS, eidS, colS, E);

    // ---- weight prep ----
    cvt_bf16<<<(256 * 384 + 255) / 256, 256, 0, stream>>>(edge_W0, eW0h, 256 * 384);
    cvt_bf16<<<(256 * 384 + 255) / 256, 256, 0, stream>>>(edge_W1, eW1h, 256 * 384);
    cvt_bf16<<<(32 * 384 + 255) / 256, 256, 0, stream>>>(edge_Wo, eWoh, 32 * 384);
    cvt_bf16<<<(256 * 256 + 255) / 256, 256, 0, stream>>>(node_W0, nW0h, 256 * 256);
    cvt_bf16<<<(256 * 256 + 255) / 256, 256, 0, stream>>>(node_W1, nW1h, 256 * 256);
    cvt_bf16<<<(32 * 768 + 255) / 256, 256, 0, stream>>>(node_Wo, nWoh, 32 * 768);
    pack_kan_bf16<<<(256 * 256 + 255) / 256, 256, 0, stream>>>(base_W0, spline_W0, Wc0h, 256 * 256);
    pack_kan_bf16<<<(256 * 256 + 255) / 256, 256, 0, stream>>>(base_W1, spline_W1, Wc1h, 256 * 256);
    pack_kan_f32<<<(32 * 32 + 255) / 256, 256, 0, stream>>>(base_Wo, spline_Wo, Wco, 32 * 32);

    // ---- layer 0 ----
    hipMemsetAsync(agg, 0, (size_t)N * 256 * sizeof(float), stream);
    node_mfma<256><<<nb64, 256, 0, stream>>>(x, nW0h, node_b0, xt, N);
    edge_mfma256_s<<<eb64, 256, 0, stream>>>(edge_attr, eW0h, edge_b0, xt, rowS, colS, eidS, agg, E);
    kan_mfma256<<<nb64, 256, 0, stream>>>(agg, Wc0h, h0, N);

    // ---- layer 1 ----
    hipMemsetAsync(agg, 0, (size_t)N * 256 * sizeof(float), stream);
    node_mfma<256><<<nb64, 256, 0, stream>>>(h0, nW1h, node_b1, xt, N);
    edge_mfma256_s<<<eb64, 256, 0, stream>>>(edge_attr, eW1h, edge_b1, xt, rowS, colS, eidS, agg, E);
    kan_mfma256<<<nb64, 256, 0, stream>>>(agg, Wc1h, h1, N);

    // ---- output layer ----
    hipMemsetAsync(agg, 0, (size_t)N * 32 * sizeof(float), stream);
    node_cat_mfma<<<nb256, 256, 0, stream>>>(x, h0, h1, nWoh, node_bo, xt, N);
    edge_mfma32_s<<<eb256, 256, 0, stream>>>(edge_attr, eWoh, edge_bo, xt, rowS, colS, eidS, agg, E);
    kan_gemm32<<<nb64, 256, 0, stream>>>(agg, Wco, out, N);
}